// Round 5
// baseline (352.048 us; speedup 1.0000x reference)
//
#include <hip/hip_runtime.h>

#define N_NODES 100000
#define N_EDGES 1600000
#define F 128
#define NB_C 196            // coarse buckets = ceil(N_NODES/512)
#define CHUNK 4000
#define NBLK_BIN 400        // 400 * 4000 = 1.6M exact
#define CAP 9984            // finesort LDS capacity (mean 8163, +20 sigma)
#define NGROUP 6250         // N_NODES / 16

// ---------------- workspace layout (bytes) ----------------
// pool   : N_EDGES ints    @ 0        (6,400,000)
// offs   : 100352 ints     @ 6400000  (401,408)   per-node END offsets
// base_t : 196*400 ints    @ 6801408  (313,600)   bucket-major count matrix
// btot   : 256 ints        @ 7115008  (1,024)
// bbase  : 256 ints        @ 7116032  (1,024)
// h      : N*128 bf16      @ 7117056  (25,600,000)
// total 32,717,056 (< 32,804,864 proven available)
#define WS_V5 32717056

typedef __attribute__((ext_vector_type(8))) short short8;
typedef __attribute__((ext_vector_type(4))) float f32x4;

__device__ __forceinline__ unsigned short f2bf(float f) {
    unsigned u = __float_as_uint(f);
    return (unsigned short)((u + 0x7fffu + ((u >> 16) & 1u)) >> 16);
}

// ---------------------------------------------------------------------------
// prep: h[i][j] = bf16(feat[i][j] / out_norm[i]).  One thread per float4.
// ---------------------------------------------------------------------------
__global__ __launch_bounds__(256) void prep_h_kernel(
    const float* __restrict__ feat, const float* __restrict__ out_norm,
    unsigned short* __restrict__ h)
{
    int q = blockIdx.x * 256 + threadIdx.x;      // grid exact: N*32/256
    int row = q >> 5;
    float r = 1.0f / out_norm[row];
    float4 v = ((const float4*)feat)[q];
    ushort4 o;
    o.x = f2bf(v.x * r); o.y = f2bf(v.y * r);
    o.z = f2bf(v.z * r); o.w = f2bf(v.w * r);
    ((ushort4*)h)[q] = o;
}

// ---------------------------------------------------------------------------
// Phase 1: per-block LDS histogram over 196 coarse buckets (dst >> 9).
// Output bucket-major: base_t[bucket*400 + blk].
// ---------------------------------------------------------------------------
__global__ __launch_bounds__(256) void chist_kernel(
    const int* __restrict__ dst, int* __restrict__ base_t)
{
    __shared__ int c[NB_C];
    int t = threadIdx.x, blk = blockIdx.x;
    if (t < NB_C) c[t] = 0;
    __syncthreads();
    int e0 = blk * CHUNK;
    for (int i = t; i < CHUNK; i += 256)
        atomicAdd(&c[dst[e0 + i] >> 9], 1);
    __syncthreads();
    if (t < NB_C) base_t[t * NBLK_BIN + blk] = c[t];
}

// ---------------------------------------------------------------------------
// Phase 2a: per-bucket exclusive scan over its 400 per-block counts.
// One wave per bucket, shuffle prefix over contiguous ints. Emits bucket total.
// ---------------------------------------------------------------------------
__global__ __launch_bounds__(64) void cscan1_kernel(
    int* __restrict__ base_t, int* __restrict__ btot)
{
    int b = blockIdx.x, l = threadIdx.x;
    int carry = 0;
    #pragma unroll
    for (int r = 0; r < 7; ++r) {            // 7*64 = 448 >= 400
        int idx = r * 64 + l;
        bool ok = idx < NBLK_BIN;
        int v = ok ? base_t[b * NBLK_BIN + idx] : 0;
        int incl = v;
        #pragma unroll
        for (int off = 1; off < 64; off <<= 1) {
            int n = __shfl_up(incl, off);
            if (l >= off) incl += n;
        }
        if (ok) base_t[b * NBLK_BIN + idx] = incl - v + carry;
        carry += __shfl(incl, 63);
    }
    if (l == 0) btot[b] = carry;
}

// ---------------------------------------------------------------------------
// Phase 2b (1 tiny block): exclusive scan of 196 bucket totals -> bbase.
// ---------------------------------------------------------------------------
__global__ __launch_bounds__(256) void cscan2_kernel(
    const int* __restrict__ btot, int* __restrict__ bbase)
{
    __shared__ int sm[256];
    int t = threadIdx.x;
    int v = (t < NB_C) ? btot[t] : 0;
    sm[t] = v;
    __syncthreads();
    for (int off = 1; off < 256; off <<= 1) {
        int x = (t >= off) ? sm[t - off] : 0;
        __syncthreads();
        sm[t] += x;
        __syncthreads();
    }
    if (t < NB_C) bbase[t] = sm[t] - v;
    if (t == 0) bbase[NB_C] = N_EDGES;
}

// ---------------------------------------------------------------------------
// Phase 3: scatter packed edges ((dst&511)<<17 | src) bucket-grouped.
// ---------------------------------------------------------------------------
__global__ __launch_bounds__(256) void binscatter_kernel(
    const int* __restrict__ src, const int* __restrict__ dst,
    const int* __restrict__ base_t, const int* __restrict__ bbase,
    int* __restrict__ pool)
{
    __shared__ int cba[NB_C];
    int t = threadIdx.x, blk = blockIdx.x;
    if (t < NB_C) cba[t] = bbase[t] + base_t[t * NBLK_BIN + blk];
    __syncthreads();
    int e0 = blk * CHUNK;
    for (int i = t; i < CHUNK; i += 256) {
        int d = dst[e0 + i];
        int s = src[e0 + i];
        int b = d >> 9;
        int pos = atomicAdd(&cba[b], 1);
        pool[pos] = ((d & 511) << 17) | s;
    }
}

// ---------------------------------------------------------------------------
// Phase 4: per-bucket fine counting sort, LDS-staged; sorted src back into
// pool in place + per-node END offsets. LDS 46 KB.
// ---------------------------------------------------------------------------
__global__ __launch_bounds__(1024) void finesort_kernel(
    int* __restrict__ pool, const int* __restrict__ bbase,
    int* __restrict__ offs)
{
    __shared__ int pairs[CAP];
    __shared__ int fcnt[512];
    __shared__ int s0[512];
    __shared__ int sexcl[512];
    int t = threadIdx.x, b = blockIdx.x;
    int beg = bbase[b];
    int end = bbase[b + 1];
    int cnt = end - beg;
    if (cnt > CAP) cnt = CAP;   // statistically unreachable
    for (int i = t; i < cnt; i += 1024) pairs[i] = pool[beg + i];
    if (t < 512) fcnt[t] = 0;
    __syncthreads();
    for (int i = t; i < cnt; i += 1024) atomicAdd(&fcnt[pairs[i] >> 17], 1);
    __syncthreads();
    if (t < 512) s0[t] = fcnt[t];
    __syncthreads();
    for (int off = 1; off < 512; off <<= 1) {
        int v = (t >= off && t < 512) ? s0[t - off] : 0;
        __syncthreads();
        if (t < 512) s0[t] += v;
        __syncthreads();
    }
    int node0 = b << 9;
    if (t < 512) {
        sexcl[t] = beg + s0[t] - fcnt[t];
        int node = node0 + t;
        if (node < N_NODES) offs[node] = beg + s0[t];   // inclusive END
    }
    __syncthreads();
    for (int i = t; i < cnt; i += 1024) {
        int p = pairs[i];
        int pos = atomicAdd(&sexcl[p >> 17], 1);
        pool[pos] = p & 0x1FFFF;
    }
}

// ---------------------------------------------------------------------------
// Fused gather + MFMA transform:
//   out[n] = (sum_{e in list(n)} h[src_e]) * (1/in_norm[n]) @ W^T + b
// Wave gathers its 16 nodes into fp32 regs, stages bf16 rows in a padded
// per-wave LDS tile (row stride 136 shorts -> bank-balanced b128 reads),
// then the proven 16x16x32 MFMA tile writes out directly. No agg round-trip.
// LDS: 32 KB W + 17.4 KB stage = 49.4 KB -> 3 blocks/CU.
// ---------------------------------------------------------------------------
__global__ __launch_bounds__(256) void fused_gt_kernel(
    const unsigned short* __restrict__ h, const int* __restrict__ offs,
    const int* __restrict__ ssrc, const float* __restrict__ in_norm,
    const float* __restrict__ W, const float* __restrict__ bias,
    float* __restrict__ out)
{
    __shared__ short Wb[F * F];                      // 32 KB, chunk-XOR swizzled
    __shared__ __align__(16) unsigned stage[4][16 * 68]; // 4 waves x 16 rows x 68 uints

    const int t = threadIdx.x;
    #pragma unroll
    for (int i = 0; i < 8; ++i) {
        int c = t + i * 256;
        int n = c >> 4, kc = c & 15;
        const float4* wp = (const float4*)(W + n * F + kc * 8);
        float4 w0 = wp[0], w1 = wp[1];
        short8 v;
        v[0] = (short)f2bf(w0.x); v[1] = (short)f2bf(w0.y);
        v[2] = (short)f2bf(w0.z); v[3] = (short)f2bf(w0.w);
        v[4] = (short)f2bf(w1.x); v[5] = (short)f2bf(w1.y);
        v[6] = (short)f2bf(w1.z); v[7] = (short)f2bf(w1.w);
        *(short8*)&Wb[n * F + ((kc ^ (n & 15)) * 8)] = v;
    }
    __syncthreads();

    const int wave = t >> 6, lane = t & 63;
    const int group = blockIdx.x * 4 + wave;         // 16-node group
    const bool valid = group < NGROUP;
    const int n0 = valid ? group * 16 : 0;
    const unsigned* hp = (const unsigned*)h;
    unsigned* st = &stage[wave][0];

    // Gather 16 node rows; stage each as bf16 immediately (releases regs).
    for (int i = 0; i < 16; ++i) {
        int node = n0 + i;
        int start = 0, end = 0;
        if (valid) {
            start = (node == 0) ? 0 : offs[node - 1];
            end = offs[node];
        }
        float ax = 0.f, ay = 0.f;
        int e = start;
        for (; e + 3 < end; e += 4) {
            unsigned u0 = hp[(size_t)ssrc[e]     * 64 + lane];
            unsigned u1 = hp[(size_t)ssrc[e + 1] * 64 + lane];
            unsigned u2 = hp[(size_t)ssrc[e + 2] * 64 + lane];
            unsigned u3 = hp[(size_t)ssrc[e + 3] * 64 + lane];
            ax += __uint_as_float(u0 << 16) + __uint_as_float(u1 << 16)
                + __uint_as_float(u2 << 16) + __uint_as_float(u3 << 16);
            ay += __uint_as_float(u0 & 0xffff0000u) + __uint_as_float(u1 & 0xffff0000u)
                + __uint_as_float(u2 & 0xffff0000u) + __uint_as_float(u3 & 0xffff0000u);
        }
        for (; e < end; ++e) {
            unsigned u = hp[(size_t)ssrc[e] * 64 + lane];
            ax += __uint_as_float(u << 16);
            ay += __uint_as_float(u & 0xffff0000u);
        }
        float rin = valid ? 1.0f / in_norm[node] : 0.f;
        unsigned lo = f2bf(ax * rin);
        unsigned hi = f2bf(ay * rin);
        st[i * 68 + lane] = lo | (hi << 16);   // row i, cols 2*lane, 2*lane+1
    }

    // Per-wave LDS RAW fence (stage written/read only by this wave).
    __asm__ volatile("s_waitcnt lgkmcnt(0)" ::: "memory");

    const int m = lane & 15, q = lane >> 4;
    const short* sts = (const short*)st;

    short8 afrag[4];
    #pragma unroll
    for (int s = 0; s < 4; ++s) {
        int k0 = s * 32 + q * 8;
        afrag[s] = *(const short8*)&sts[m * 136 + k0];
    }

    f32x4 acc[8];
    #pragma unroll
    for (int c = 0; c < 8; ++c) { f32x4 z = {0.f, 0.f, 0.f, 0.f}; acc[c] = z; }

    #pragma unroll
    for (int s = 0; s < 4; ++s) {
        const int kc = s * 4 + q;
        #pragma unroll
        for (int c = 0; c < 8; ++c) {
            const int n = c * 16 + m;
            short8 bfrag = *(const short8*)&Wb[n * F + ((kc ^ m) * 8)];
            acc[c] = __builtin_amdgcn_mfma_f32_16x16x32_bf16(
                afrag[s], bfrag, acc[c], 0, 0, 0);
        }
    }

    if (valid) {
        #pragma unroll
        for (int c = 0; c < 8; ++c) {
            const float bc = bias[c * 16 + m];
            #pragma unroll
            for (int r = 0; r < 4; ++r) {
                out[(size_t)(n0 + q * 4 + r) * F + c * 16 + m] = acc[c][r] + bc;
            }
        }
    }
}

// ---------------------------------------------------------------------------
// Parachute fallback (tiny ws): R1 atomic scatter + fp32 VALU transform.
// ---------------------------------------------------------------------------
__global__ __launch_bounds__(256) void scatter_kernel(
    const float* __restrict__ feat, const float* __restrict__ out_norm,
    const int* __restrict__ src, const int* __restrict__ dst,
    float* __restrict__ agg)
{
    const int wave = threadIdx.x >> 6;
    const int lane = threadIdx.x & 63;
    const int e = blockIdx.x * 4 + wave;
    const int s = src[e];
    const int d = dst[e];
    const float rn = 1.0f / out_norm[s];
    const float2 v = ((const float2*)(feat + (size_t)s * F))[lane];
    float* ap = agg + (size_t)d * F + lane * 2;
    unsafeAtomicAdd(ap,     v.x * rn);
    unsafeAtomicAdd(ap + 1, v.y * rn);
}

__global__ __launch_bounds__(256) void transform_kernel(
    float* __restrict__ out, const float* __restrict__ in_norm,
    const float* __restrict__ W, const float* __restrict__ bias)
{
    __shared__ float Wt[F * F];
    const int t = threadIdx.x;
    #pragma unroll
    for (int i = 0; i < (F * F) / 256; ++i) {
        int idx = t + i * 256;
        int j = idx >> 7;
        int k = idx & (F - 1);
        Wt[k * F + j] = W[idx];
    }
    __syncthreads();
    const int wave = t >> 6, lane = t & 63;
    const float b0 = bias[lane];
    const float b1 = bias[lane + 64];
    const int ngroups = N_NODES / 16;
    for (int g = blockIdx.x; g < ngroups; g += gridDim.x) {
        const int r = g * 16 + wave * 4;
        const float4* a0 = (const float4*)(out + (size_t)r * F);
        const float4* a1 = a0 + F / 4;
        const float4* a2 = a0 + 2 * (F / 4);
        const float4* a3 = a0 + 3 * (F / 4);
        float acc00 = 0.f, acc01 = 0.f, acc10 = 0.f, acc11 = 0.f;
        float acc20 = 0.f, acc21 = 0.f, acc30 = 0.f, acc31 = 0.f;
        for (int k4 = 0; k4 < F / 4; ++k4) {
            const float4 x0 = a0[k4]; const float4 x1 = a1[k4];
            const float4 x2 = a2[k4]; const float4 x3 = a3[k4];
            const float xs0[4] = {x0.x, x0.y, x0.z, x0.w};
            const float xs1[4] = {x1.x, x1.y, x1.z, x1.w};
            const float xs2[4] = {x2.x, x2.y, x2.z, x2.w};
            const float xs3[4] = {x3.x, x3.y, x3.z, x3.w};
            #pragma unroll
            for (int kk = 0; kk < 4; ++kk) {
                const int k = k4 * 4 + kk;
                const float w0 = Wt[k * F + lane];
                const float w1 = Wt[k * F + 64 + lane];
                acc00 = fmaf(xs0[kk], w0, acc00); acc01 = fmaf(xs0[kk], w1, acc01);
                acc10 = fmaf(xs1[kk], w0, acc10); acc11 = fmaf(xs1[kk], w1, acc11);
                acc20 = fmaf(xs2[kk], w0, acc20); acc21 = fmaf(xs2[kk], w1, acc21);
                acc30 = fmaf(xs3[kk], w0, acc30); acc31 = fmaf(xs3[kk], w1, acc31);
            }
        }
        const float i0 = 1.0f / in_norm[r + 0];
        const float i1 = 1.0f / in_norm[r + 1];
        const float i2 = 1.0f / in_norm[r + 2];
        const float i3 = 1.0f / in_norm[r + 3];
        out[(size_t)(r + 0) * F + lane]      = acc00 * i0 + b0;
        out[(size_t)(r + 0) * F + 64 + lane] = acc01 * i0 + b1;
        out[(size_t)(r + 1) * F + lane]      = acc10 * i1 + b0;
        out[(size_t)(r + 1) * F + 64 + lane] = acc11 * i1 + b1;
        out[(size_t)(r + 2) * F + lane]      = acc20 * i2 + b0;
        out[(size_t)(r + 2) * F + 64 + lane] = acc21 * i2 + b1;
        out[(size_t)(r + 3) * F + lane]      = acc30 * i3 + b0;
        out[(size_t)(r + 3) * F + 64 + lane] = acc31 * i3 + b1;
    }
}

extern "C" void kernel_launch(void* const* d_in, const int* in_sizes, int n_in,
                              void* d_out, int out_size, void* d_ws, size_t ws_size,
                              hipStream_t stream) {
    const float* feat     = (const float*)d_in[0];
    const float* in_norm  = (const float*)d_in[1];
    const float* out_norm = (const float*)d_in[2];
    const int*   src      = (const int*)d_in[3];
    const int*   dst      = (const int*)d_in[4];
    const float* W        = (const float*)d_in[5];
    const float* b        = (const float*)d_in[6];
    float* out = (float*)d_out;

    if (ws_size >= (size_t)WS_V5) {
        char* w = (char*)d_ws;
        int*            pool   = (int*)(w + 0);
        int*            offs   = (int*)(w + 6400000);
        int*            base_t = (int*)(w + 6801408);
        int*            btot   = (int*)(w + 7115008);
        int*            bbase  = (int*)(w + 7116032);
        unsigned short* h      = (unsigned short*)(w + 7117056);

        prep_h_kernel<<<(N_NODES * 32) / 256, 256, 0, stream>>>(feat, out_norm, h);
        chist_kernel<<<NBLK_BIN, 256, 0, stream>>>(dst, base_t);
        cscan1_kernel<<<NB_C, 64, 0, stream>>>(base_t, btot);
        cscan2_kernel<<<1, 256, 0, stream>>>(btot, bbase);
        binscatter_kernel<<<NBLK_BIN, 256, 0, stream>>>(src, dst, base_t, bbase, pool);
        finesort_kernel<<<NB_C, 1024, 0, stream>>>(pool, bbase, offs);
        fused_gt_kernel<<<(NGROUP + 3) / 4, 256, 0, stream>>>(
            h, offs, pool, in_norm, W, b, out);
    } else {
        hipMemsetAsync(out, 0, (size_t)N_NODES * F * sizeof(float), stream);
        scatter_kernel<<<N_EDGES / 4, 256, 0, stream>>>(feat, out_norm, src, dst, out);
        transform_kernel<<<2048, 256, 0, stream>>>(out, in_norm, W, b);
    }
}

// Round 6
// 254.481 us; speedup vs baseline: 1.3834x; 1.3834x over previous
//
#include <hip/hip_runtime.h>

#define N_NODES 100000
#define N_EDGES 1600000
#define F 128
#define NB_C 196            // coarse buckets = ceil(N_NODES/512)
#define CHUNK 4000
#define NBLK_BIN 400        // 400 * 4000 = 1.6M exact
#define CAP 9984            // finesort LDS capacity (mean 8163, +20 sigma)
#define NGROUP 6250         // N_NODES / 16

// ---------------- workspace layout (bytes) ----------------
// pool   : N_EDGES ints    @ 0        (6,400,000)
// offs   : 100352 ints     @ 6400000  (401,408)   per-node END offsets
// base_t : 196*400 ints    @ 6801408  (313,600)   bucket-major count matrix
// btot   : 256 ints        @ 7115008  (1,024)
// bbase  : 256 ints        @ 7116032  (1,024)
// h      : N*128 bf16      @ 7117056  (25,600,000)
// total 32,717,056 (< 32,804,864 proven available)
#define WS_V6 32717056

typedef __attribute__((ext_vector_type(8))) short short8;
typedef __attribute__((ext_vector_type(4))) float f32x4;

__device__ __forceinline__ unsigned short f2bf(float f) {
    unsigned u = __float_as_uint(f);
    return (unsigned short)((u + 0x7fffu + ((u >> 16) & 1u)) >> 16);
}

// ---------------------------------------------------------------------------
// prep: h[i][j] = bf16(feat[i][j] / out_norm[i]).  One thread per float4.
// ---------------------------------------------------------------------------
__global__ __launch_bounds__(256) void prep_h_kernel(
    const float* __restrict__ feat, const float* __restrict__ out_norm,
    unsigned short* __restrict__ h)
{
    int q = blockIdx.x * 256 + threadIdx.x;      // grid exact: N*32/256
    int row = q >> 5;
    float r = 1.0f / out_norm[row];
    float4 v = ((const float4*)feat)[q];
    ushort4 o;
    o.x = f2bf(v.x * r); o.y = f2bf(v.y * r);
    o.z = f2bf(v.z * r); o.w = f2bf(v.w * r);
    ((ushort4*)h)[q] = o;
}

// ---------------------------------------------------------------------------
// Phase 1: per-block LDS histogram over 196 coarse buckets (dst >> 9).
// Output bucket-major: base_t[bucket*400 + blk].
// ---------------------------------------------------------------------------
__global__ __launch_bounds__(256) void chist_kernel(
    const int* __restrict__ dst, int* __restrict__ base_t)
{
    __shared__ int c[NB_C];
    int t = threadIdx.x, blk = blockIdx.x;
    if (t < NB_C) c[t] = 0;
    __syncthreads();
    int e0 = blk * CHUNK;
    for (int i = t; i < CHUNK; i += 256)
        atomicAdd(&c[dst[e0 + i] >> 9], 1);
    __syncthreads();
    if (t < NB_C) base_t[t * NBLK_BIN + blk] = c[t];
}

// ---------------------------------------------------------------------------
// Phase 2a: per-bucket exclusive scan over its 400 per-block counts.
// One wave per bucket, shuffle prefix over contiguous ints. Emits bucket total.
// ---------------------------------------------------------------------------
__global__ __launch_bounds__(64) void cscan1_kernel(
    int* __restrict__ base_t, int* __restrict__ btot)
{
    int b = blockIdx.x, l = threadIdx.x;
    int carry = 0;
    #pragma unroll
    for (int r = 0; r < 7; ++r) {            // 7*64 = 448 >= 400
        int idx = r * 64 + l;
        bool ok = idx < NBLK_BIN;
        int v = ok ? base_t[b * NBLK_BIN + idx] : 0;
        int incl = v;
        #pragma unroll
        for (int off = 1; off < 64; off <<= 1) {
            int n = __shfl_up(incl, off);
            if (l >= off) incl += n;
        }
        if (ok) base_t[b * NBLK_BIN + idx] = incl - v + carry;
        carry += __shfl(incl, 63);
    }
    if (l == 0) btot[b] = carry;
}

// ---------------------------------------------------------------------------
// Phase 2b (1 tiny block): exclusive scan of 196 bucket totals -> bbase.
// ---------------------------------------------------------------------------
__global__ __launch_bounds__(256) void cscan2_kernel(
    const int* __restrict__ btot, int* __restrict__ bbase)
{
    __shared__ int sm[256];
    int t = threadIdx.x;
    int v = (t < NB_C) ? btot[t] : 0;
    sm[t] = v;
    __syncthreads();
    for (int off = 1; off < 256; off <<= 1) {
        int x = (t >= off) ? sm[t - off] : 0;
        __syncthreads();
        sm[t] += x;
        __syncthreads();
    }
    if (t < NB_C) bbase[t] = sm[t] - v;
    if (t == 0) bbase[NB_C] = N_EDGES;
}

// ---------------------------------------------------------------------------
// Phase 3: scatter packed edges ((dst&511)<<17 | src) bucket-grouped.
// ---------------------------------------------------------------------------
__global__ __launch_bounds__(256) void binscatter_kernel(
    const int* __restrict__ src, const int* __restrict__ dst,
    const int* __restrict__ base_t, const int* __restrict__ bbase,
    int* __restrict__ pool)
{
    __shared__ int cba[NB_C];
    int t = threadIdx.x, blk = blockIdx.x;
    if (t < NB_C) cba[t] = bbase[t] + base_t[t * NBLK_BIN + blk];
    __syncthreads();
    int e0 = blk * CHUNK;
    for (int i = t; i < CHUNK; i += 256) {
        int d = dst[e0 + i];
        int s = src[e0 + i];
        int b = d >> 9;
        int pos = atomicAdd(&cba[b], 1);
        pool[pos] = ((d & 511) << 17) | s;
    }
}

// ---------------------------------------------------------------------------
// Phase 4: per-bucket fine counting sort, LDS-staged; sorted src back into
// pool in place + per-node END offsets. LDS 46 KB.
// ---------------------------------------------------------------------------
__global__ __launch_bounds__(1024) void finesort_kernel(
    int* __restrict__ pool, const int* __restrict__ bbase,
    int* __restrict__ offs)
{
    __shared__ int pairs[CAP];
    __shared__ int fcnt[512];
    __shared__ int s0[512];
    __shared__ int sexcl[512];
    int t = threadIdx.x, b = blockIdx.x;
    int beg = bbase[b];
    int end = bbase[b + 1];
    int cnt = end - beg;
    if (cnt > CAP) cnt = CAP;   // statistically unreachable
    for (int i = t; i < cnt; i += 1024) pairs[i] = pool[beg + i];
    if (t < 512) fcnt[t] = 0;
    __syncthreads();
    for (int i = t; i < cnt; i += 1024) atomicAdd(&fcnt[pairs[i] >> 17], 1);
    __syncthreads();
    if (t < 512) s0[t] = fcnt[t];
    __syncthreads();
    for (int off = 1; off < 512; off <<= 1) {
        int v = (t >= off && t < 512) ? s0[t - off] : 0;
        __syncthreads();
        if (t < 512) s0[t] += v;
        __syncthreads();
    }
    int node0 = b << 9;
    if (t < 512) {
        sexcl[t] = beg + s0[t] - fcnt[t];
        int node = node0 + t;
        if (node < N_NODES) offs[node] = beg + s0[t];   // inclusive END
    }
    __syncthreads();
    for (int i = t; i < cnt; i += 1024) {
        int p = pairs[i];
        int pos = atomicAdd(&sexcl[p >> 17], 1);
        pool[pos] = p & 0x1FFFF;
    }
}

// ---------------------------------------------------------------------------
// Gather (standalone, high-occupancy — R4-proven): one wave per node; lane
// reads one uint (2 bf16) per incident row. 1/in_norm folded in; agg written
// exactly once, no atomics. Latency-bound on random h rows -> needs the 70%
// occupancy this 0-LDS kernel gets (fusing it into the MFMA kernel dropped
// occupancy to 23% and regressed 2.6x — R5 post-mortem).
// ---------------------------------------------------------------------------
__global__ __launch_bounds__(256) void gather_bf16_kernel(
    const unsigned short* __restrict__ h, const int* __restrict__ offs,
    const int* __restrict__ ssrc, const float* __restrict__ in_norm,
    float* __restrict__ agg)
{
    const int wave = threadIdx.x >> 6, lane = threadIdx.x & 63;
    const int i = blockIdx.x * 4 + wave;      // grid = N/4 exact
    const int start = (i == 0) ? 0 : offs[i - 1];
    const int end = offs[i];
    const unsigned* hp = (const unsigned*)h;
    float ax = 0.f, ay = 0.f;
    int e = start;
    for (; e + 3 < end; e += 4) {
        unsigned u0 = hp[(size_t)ssrc[e]     * 64 + lane];
        unsigned u1 = hp[(size_t)ssrc[e + 1] * 64 + lane];
        unsigned u2 = hp[(size_t)ssrc[e + 2] * 64 + lane];
        unsigned u3 = hp[(size_t)ssrc[e + 3] * 64 + lane];
        ax += __uint_as_float(u0 << 16) + __uint_as_float(u1 << 16)
            + __uint_as_float(u2 << 16) + __uint_as_float(u3 << 16);
        ay += __uint_as_float(u0 & 0xffff0000u) + __uint_as_float(u1 & 0xffff0000u)
            + __uint_as_float(u2 & 0xffff0000u) + __uint_as_float(u3 & 0xffff0000u);
    }
    for (; e < end; ++e) {
        unsigned u = hp[(size_t)ssrc[e] * 64 + lane];
        ax += __uint_as_float(u << 16);
        ay += __uint_as_float(u & 0xffff0000u);
    }
    const float rin = 1.0f / in_norm[i];
    float2 o; o.x = ax * rin; o.y = ay * rin;
    ((float2*)agg)[(size_t)i * 64 + lane] = o;
}

// ---------------------------------------------------------------------------
// MFMA transform (in-place on d_out, R3/R4-proven): out = agg @ W^T + b.
// rin already applied by gather. 32 KB LDS, chunk-XOR swizzle.
// ---------------------------------------------------------------------------
__global__ __launch_bounds__(256) void transform_mfma_kernel(
    float* __restrict__ out, const float* __restrict__ W,
    const float* __restrict__ bias)
{
    __shared__ short Wb[F * F];   // 32 KB bf16, chunk-XOR swizzled
    const int t = threadIdx.x;
    #pragma unroll
    for (int i = 0; i < 8; ++i) {
        int c = t + i * 256;
        int n = c >> 4, kc = c & 15;
        const float4* wp = (const float4*)(W + n * F + kc * 8);
        float4 w0 = wp[0], w1 = wp[1];
        short8 v;
        v[0] = (short)f2bf(w0.x); v[1] = (short)f2bf(w0.y);
        v[2] = (short)f2bf(w0.z); v[3] = (short)f2bf(w0.w);
        v[4] = (short)f2bf(w1.x); v[5] = (short)f2bf(w1.y);
        v[6] = (short)f2bf(w1.z); v[7] = (short)f2bf(w1.w);
        *(short8*)&Wb[n * F + ((kc ^ (n & 15)) * 8)] = v;
    }
    __syncthreads();

    const int wave = t >> 6, lane = t & 63;
    const int wblk = blockIdx.x * 4 + wave;
    if (wblk >= NGROUP) return;
    const int r0 = wblk * 16;
    const int m = lane & 15, q = lane >> 4;
    const float4* arow = (const float4*)(out + (size_t)(r0 + m) * F);

    short8 afrag[4];
    #pragma unroll
    for (int s = 0; s < 4; ++s) {
        int k0 = s * 32 + q * 8;
        float4 x0 = arow[k0 >> 2];
        float4 x1 = arow[(k0 >> 2) + 1];
        short8 a;
        a[0] = (short)f2bf(x0.x); a[1] = (short)f2bf(x0.y);
        a[2] = (short)f2bf(x0.z); a[3] = (short)f2bf(x0.w);
        a[4] = (short)f2bf(x1.x); a[5] = (short)f2bf(x1.y);
        a[6] = (short)f2bf(x1.z); a[7] = (short)f2bf(x1.w);
        afrag[s] = a;
    }

    f32x4 acc[8];
    #pragma unroll
    for (int c = 0; c < 8; ++c) { f32x4 z = {0.f, 0.f, 0.f, 0.f}; acc[c] = z; }

    #pragma unroll
    for (int s = 0; s < 4; ++s) {
        const int kc = s * 4 + q;
        #pragma unroll
        for (int c = 0; c < 8; ++c) {
            const int n = c * 16 + m;
            short8 bfrag = *(const short8*)&Wb[n * F + ((kc ^ m) * 8)];
            acc[c] = __builtin_amdgcn_mfma_f32_16x16x32_bf16(
                afrag[s], bfrag, acc[c], 0, 0, 0);
        }
    }

    #pragma unroll
    for (int c = 0; c < 8; ++c) {
        const float bc = bias[c * 16 + m];
        #pragma unroll
        for (int r = 0; r < 4; ++r) {
            out[(size_t)(r0 + q * 4 + r) * F + c * 16 + m] = acc[c][r] + bc;
        }
    }
}

// ---------------------------------------------------------------------------
// Parachute fallback (tiny ws): R1 atomic scatter + fp32 VALU transform.
// ---------------------------------------------------------------------------
__global__ __launch_bounds__(256) void scatter_kernel(
    const float* __restrict__ feat, const float* __restrict__ out_norm,
    const int* __restrict__ src, const int* __restrict__ dst,
    float* __restrict__ agg)
{
    const int wave = threadIdx.x >> 6;
    const int lane = threadIdx.x & 63;
    const int e = blockIdx.x * 4 + wave;
    const int s = src[e];
    const int d = dst[e];
    const float rn = 1.0f / out_norm[s];
    const float2 v = ((const float2*)(feat + (size_t)s * F))[lane];
    float* ap = agg + (size_t)d * F + lane * 2;
    unsafeAtomicAdd(ap,     v.x * rn);
    unsafeAtomicAdd(ap + 1, v.y * rn);
}

__global__ __launch_bounds__(256) void transform_kernel(
    float* __restrict__ out, const float* __restrict__ in_norm,
    const float* __restrict__ W, const float* __restrict__ bias)
{
    __shared__ float Wt[F * F];
    const int t = threadIdx.x;
    #pragma unroll
    for (int i = 0; i < (F * F) / 256; ++i) {
        int idx = t + i * 256;
        int j = idx >> 7;
        int k = idx & (F - 1);
        Wt[k * F + j] = W[idx];
    }
    __syncthreads();
    const int wave = t >> 6, lane = t & 63;
    const float b0 = bias[lane];
    const float b1 = bias[lane + 64];
    const int ngroups = N_NODES / 16;
    for (int g = blockIdx.x; g < ngroups; g += gridDim.x) {
        const int r = g * 16 + wave * 4;
        const float4* a0 = (const float4*)(out + (size_t)r * F);
        const float4* a1 = a0 + F / 4;
        const float4* a2 = a0 + 2 * (F / 4);
        const float4* a3 = a0 + 3 * (F / 4);
        float acc00 = 0.f, acc01 = 0.f, acc10 = 0.f, acc11 = 0.f;
        float acc20 = 0.f, acc21 = 0.f, acc30 = 0.f, acc31 = 0.f;
        for (int k4 = 0; k4 < F / 4; ++k4) {
            const float4 x0 = a0[k4]; const float4 x1 = a1[k4];
            const float4 x2 = a2[k4]; const float4 x3 = a3[k4];
            const float xs0[4] = {x0.x, x0.y, x0.z, x0.w};
            const float xs1[4] = {x1.x, x1.y, x1.z, x1.w};
            const float xs2[4] = {x2.x, x2.y, x2.z, x2.w};
            const float xs3[4] = {x3.x, x3.y, x3.z, x3.w};
            #pragma unroll
            for (int kk = 0; kk < 4; ++kk) {
                const int k = k4 * 4 + kk;
                const float w0 = Wt[k * F + lane];
                const float w1 = Wt[k * F + 64 + lane];
                acc00 = fmaf(xs0[kk], w0, acc00); acc01 = fmaf(xs0[kk], w1, acc01);
                acc10 = fmaf(xs1[kk], w0, acc10); acc11 = fmaf(xs1[kk], w1, acc11);
                acc20 = fmaf(xs2[kk], w0, acc20); acc21 = fmaf(xs2[kk], w1, acc21);
                acc30 = fmaf(xs3[kk], w0, acc30); acc31 = fmaf(xs3[kk], w1, acc31);
            }
        }
        const float i0 = 1.0f / in_norm[r + 0];
        const float i1 = 1.0f / in_norm[r + 1];
        const float i2 = 1.0f / in_norm[r + 2];
        const float i3 = 1.0f / in_norm[r + 3];
        out[(size_t)(r + 0) * F + lane]      = acc00 * i0 + b0;
        out[(size_t)(r + 0) * F + 64 + lane] = acc01 * i0 + b1;
        out[(size_t)(r + 1) * F + lane]      = acc10 * i1 + b0;
        out[(size_t)(r + 1) * F + 64 + lane] = acc11 * i1 + b1;
        out[(size_t)(r + 2) * F + lane]      = acc20 * i2 + b0;
        out[(size_t)(r + 2) * F + 64 + lane] = acc21 * i2 + b1;
        out[(size_t)(r + 3) * F + lane]      = acc30 * i3 + b0;
        out[(size_t)(r + 3) * F + 64 + lane] = acc31 * i3 + b1;
    }
}

extern "C" void kernel_launch(void* const* d_in, const int* in_sizes, int n_in,
                              void* d_out, int out_size, void* d_ws, size_t ws_size,
                              hipStream_t stream) {
    const float* feat     = (const float*)d_in[0];
    const float* in_norm  = (const float*)d_in[1];
    const float* out_norm = (const float*)d_in[2];
    const int*   src      = (const int*)d_in[3];
    const int*   dst      = (const int*)d_in[4];
    const float* W        = (const float*)d_in[5];
    const float* b        = (const float*)d_in[6];
    float* out = (float*)d_out;

    if (ws_size >= (size_t)WS_V6) {
        char* w = (char*)d_ws;
        int*            pool   = (int*)(w + 0);
        int*            offs   = (int*)(w + 6400000);
        int*            base_t = (int*)(w + 6801408);
        int*            btot   = (int*)(w + 7115008);
        int*            bbase  = (int*)(w + 7116032);
        unsigned short* h      = (unsigned short*)(w + 7117056);

        prep_h_kernel<<<(N_NODES * 32) / 256, 256, 0, stream>>>(feat, out_norm, h);
        chist_kernel<<<NBLK_BIN, 256, 0, stream>>>(dst, base_t);
        cscan1_kernel<<<NB_C, 64, 0, stream>>>(base_t, btot);
        cscan2_kernel<<<1, 256, 0, stream>>>(btot, bbase);
        binscatter_kernel<<<NBLK_BIN, 256, 0, stream>>>(src, dst, base_t, bbase, pool);
        finesort_kernel<<<NB_C, 1024, 0, stream>>>(pool, bbase, offs);
        gather_bf16_kernel<<<N_NODES / 4, 256, 0, stream>>>(h, offs, pool, in_norm, out);
        transform_mfma_kernel<<<(NGROUP + 3) / 4, 256, 0, stream>>>(out, W, b);
    } else {
        hipMemsetAsync(out, 0, (size_t)N_NODES * F * sizeof(float), stream);
        scatter_kernel<<<N_EDGES / 4, 256, 0, stream>>>(feat, out_norm, src, dst, out);
        transform_kernel<<<2048, 256, 0, stream>>>(out, in_norm, W, b);
    }
}